// Round 5
// baseline (967.427 us; speedup 1.0000x reference)
//
#include <hip/hip_runtime.h>

#define N_TRAIN 100000
#define DIM 768
#define NQ 1024
#define BN 48                  // cols per chunk; LDS 74KB -> 2 WGs/CU
#define NCHUNK 2084            // ceil(100000/48), tail chunk has 16 valid
#define MARGIN 6.0f
#define MAXC 65536

typedef __bf16 bf16x8 __attribute__((ext_vector_type(8)));
typedef float f32x4 __attribute__((ext_vector_type(4)));
typedef unsigned short u16x8 __attribute__((ext_vector_type(8)));

__device__ __forceinline__ unsigned short f2bf(float f) {
  unsigned int u = __builtin_bit_cast(unsigned int, f);
  u = (u + 0x7FFFu + ((u >> 16) & 1u)) >> 16;   // RNE fp32->bf16
  return (unsigned short)u;
}
__device__ __forceinline__ float bf2f(unsigned short h) {
  return __builtin_bit_cast(float, (unsigned int)h << 16);
}
// monotonic float<->uint for atomicMin over possibly-negative floats
__device__ __forceinline__ unsigned int fenc(float f) {
  unsigned int u = __builtin_bit_cast(unsigned int, f);
  return (u & 0x80000000u) ? ~u : (u | 0x80000000u);
}
__device__ __forceinline__ float fdec(unsigned int u) {
  u = (u & 0x80000000u) ? (u & 0x7FFFFFFFu) : ~u;
  return __builtin_bit_cast(float, u);
}

// ---------------- init ----------------
__global__ void initK(unsigned long long* res, unsigned int* gmin, unsigned int* cnt) {
  int t = threadIdx.x;
  res[t] = ~0ull;
  gmin[t] = 0xFFFFFFFFu;
  if (t == 0) *cnt = 0u;
}

// ------- convert queries to bf16, pre-swizzled MFMA A-fragment layout -------
// mfma_f32_16x16x32_bf16 A-operand: lane l -> row=l&15, k=(l>>4)*8..+7
// Asw[fragid=mf*24+ks][lane][8 bf16] -> coalesced 1KB wave loads, L2-resident
__global__ void convA(const float* __restrict__ x, unsigned short* __restrict__ Asw) {
  int t = blockIdx.x * 256 + threadIdx.x;   // 0..98303
  int l = t & 63;
  int fragid = t >> 6;                      // 0..1535
  int mf = fragid / 24;
  int ks = fragid - mf * 24;
  int row = mf * 16 + (l & 15);
  int k = ks * 32 + (l >> 4) * 8;
  const float* src = x + (size_t)row * DIM + k;
  u16x8 h;
#pragma unroll
  for (int i = 0; i < 8; ++i) h[i] = f2bf(src[i]);
  *(u16x8*)(Asw + (size_t)fragid * 512 + l * 8) = h;
}

// ---------------- Pass A: approx bf16 GEMM + block-min ----------------
// One WG per 48-column chunk. B-tile (full K=768) staged ONCE in 74KB LDS
// (bf16, XOR-swizzled); barrier-free k-loop reads A-frags from L2.
// Output layout bmin[chunk][q][cf]: WG-contiguous writes, plain stores so L2
// write-combines full lines (nt stores caused 52x write amplification in R4).
__global__ __launch_bounds__(512, 4) void passA(
    const float* __restrict__ Xt, const unsigned short* __restrict__ Asw,
    float* __restrict__ bmin, int fine) {
  __shared__ __align__(16) unsigned short Bs[BN * DIM];  // 73728 B
  __shared__ float t2p[BN][8];
  __shared__ float t2s[BN];
  const int tid = threadIdx.x;
  const int chunk = blockIdx.x;

  // ---- stage: 48 train rows -> bf16 LDS (swizzled) + sum-of-squares ----
  if (tid < 384) {
    const int c = tid >> 3;      // local column (train row) 0..47
    const int sl = tid & 7;      // k-slice
    const int n = chunk * BN + c;
    float ss = 0.f;
    if (n < N_TRAIN) {
      const float* src = Xt + (size_t)n * DIM + sl * 8;
#pragma unroll
      for (int j = 0; j < 12; ++j) {
        f32x4 v0 = *(const f32x4*)(src + j * 64);
        f32x4 v1 = *(const f32x4*)(src + j * 64 + 4);
        u16x8 h;
        h[0] = f2bf(v0[0]); h[1] = f2bf(v0[1]); h[2] = f2bf(v0[2]); h[3] = f2bf(v0[3]);
        h[4] = f2bf(v1[0]); h[5] = f2bf(v1[1]); h[6] = f2bf(v1[2]); h[7] = f2bf(v1[3]);
#pragma unroll
        for (int i = 0; i < 8; ++i) { float f = bf2f(h[i]); ss = fmaf(f, f, ss); }
        int e = (c * DIM + sl * 8 + j * 64) ^ ((c & 7) << 3);
        *(u16x8*)(&Bs[e]) = h;
      }
    } else {
      u16x8 h;
#pragma unroll
      for (int i = 0; i < 8; ++i) h[i] = 0;
#pragma unroll
      for (int j = 0; j < 12; ++j) {
        int e = (c * DIM + sl * 8 + j * 64) ^ ((c & 7) << 3);
        *(u16x8*)(&Bs[e]) = h;
      }
    }
    t2p[c][sl] = ss;
  }
  __syncthreads();
  if (tid < BN) {
    float s = 0.f;
#pragma unroll
    for (int j = 0; j < 8; ++j) s += t2p[tid][j];
    t2s[tid] = (chunk * BN + tid < N_TRAIN) ? s : 3.0e38f;
  }
  __syncthreads();

  const int wid = tid >> 6;
  const int l = tid & 63;
  const int lc = l & 15;
  const int lg = l >> 4;

  for (int mt = 0; mt < 2; ++mt) {          // 2 m-tiles of 512 query rows
    f32x4 acc[4][3];
#pragma unroll
    for (int rf = 0; rf < 4; ++rf)
#pragma unroll
      for (int cf = 0; cf < 3; ++cf) {
        acc[rf][cf][0] = 0.f; acc[rf][cf][1] = 0.f;
        acc[rf][cf][2] = 0.f; acc[rf][cf][3] = 0.f;
      }
    const int mfbase = mt * 32 + wid * 4;   // wave owns 64 query rows = 4 row-frags
#pragma unroll
    for (int ks = 0; ks < 24; ++ks) {
      bf16x8 a[4], b[3];
#pragma unroll
      for (int rf = 0; rf < 4; ++rf)
        a[rf] = __builtin_bit_cast(bf16x8,
                  *(const u16x8*)(Asw + (size_t)((mfbase + rf) * 24 + ks) * 512 + l * 8));
#pragma unroll
      for (int cf = 0; cf < 3; ++cf) {
        int col = cf * 16 + lc;
        int idx = (col * DIM + ks * 32 + lg * 8) ^ ((col & 7) << 3);
        b[cf] = __builtin_bit_cast(bf16x8, *(const u16x8*)(&Bs[idx]));
      }
#pragma unroll
      for (int rf = 0; rf < 4; ++rf)
#pragma unroll
        for (int cf = 0; cf < 3; ++cf)
          acc[rf][cf] = __builtin_amdgcn_mfma_f32_16x16x32_bf16(a[rf], b[cf], acc[rf][cf], 0, 0, 0);
    }
    // ---- epilogue: d2' = t2 - 2*cross ; per-row mins; contiguous writes ----
    const int rowbase = mt * 512 + wid * 64;
#pragma unroll
    for (int rf = 0; rf < 4; ++rf) {
#pragma unroll
      for (int reg = 0; reg < 4; ++reg) {
        int row = rowbase + rf * 16 + lg * 4 + reg;
        if (fine) {                           // 3 blocks of 16 cols
#pragma unroll
          for (int cf = 0; cf < 3; ++cf) {
            float v = t2s[cf * 16 + lc] - 2.f * acc[rf][cf][reg];
#pragma unroll
            for (int s = 1; s < 16; s <<= 1) v = fminf(v, __shfl_xor(v, s));
            if (lc == 0)
              bmin[(size_t)chunk * (NQ * 3) + row * 3 + cf] = v;
          }
        } else {                              // one block of 48 cols
          float v = 3.0e38f;
#pragma unroll
          for (int cf = 0; cf < 3; ++cf)
            v = fminf(v, t2s[cf * 16 + lc] - 2.f * acc[rf][cf][reg]);
#pragma unroll
          for (int s = 1; s < 16; s <<= 1) v = fminf(v, __shfl_xor(v, s));
          if (lc == 0)
            bmin[(size_t)chunk * NQ + row] = v;
        }
      }
    }
  }
}

// ------- Pass B1: per-query global min (coalesced over q, atomicMin) -------
__global__ __launch_bounds__(256) void passB1(const float* __restrict__ bmin,
                                              unsigned int* __restrict__ gmin, int bpq) {
  int qg = blockIdx.x >> 4, cs = blockIdx.x & 15;
  int w = threadIdx.x >> 6, l = threadIdx.x & 63;
  int q = qg * 64 + l;
  float m = 3.0e38f;
  for (int j = cs * 4 + w; j < NCHUNK; j += 64) {
    const float* p = bmin + (size_t)j * (NQ * bpq) + q * bpq;
    for (int cf = 0; cf < bpq; ++cf) m = fminf(m, p[cf]);
  }
  __shared__ float sm[4][64];
  sm[w][l] = m;
  __syncthreads();
  if (threadIdx.x < 64) {
    float v = fminf(fminf(sm[0][l], sm[1][l]), fminf(sm[2][l], sm[3][l]));
    atomicMin(&gmin[q], fenc(v));
  }
}

// ------- Pass B2: emit candidate blocks within min+MARGIN -------
__global__ __launch_bounds__(256) void passB2(const float* __restrict__ bmin,
                                              const unsigned int* __restrict__ gmin,
                                              unsigned int* __restrict__ cnt,
                                              unsigned int* __restrict__ cand, int bpq) {
  int qg = blockIdx.x >> 4, cs = blockIdx.x & 15;
  int w = threadIdx.x >> 6, l = threadIdx.x & 63;
  int q = qg * 64 + l;
  float thr = fdec(gmin[q]) + MARGIN;
  for (int j = cs * 4 + w; j < NCHUNK; j += 64) {
    const float* p = bmin + (size_t)j * (NQ * bpq) + q * bpq;
    for (int cf = 0; cf < bpq; ++cf) {
      if (p[cf] <= thr) {
        unsigned int pos = atomicAdd(cnt, 1u);
        if (pos < MAXC) cand[pos] = ((unsigned int)q << 16) | (unsigned int)(j * bpq + cf);
      }
    }
  }
}

// ---------------- Pass C: exact fp32 re-rank of candidates ----------------
__global__ void passC(const float* __restrict__ x, const float* __restrict__ Xt,
                      const unsigned int* __restrict__ cnt, const unsigned int* __restrict__ cand,
                      unsigned long long* __restrict__ res, int cpbsh, int ncols) {
  unsigned int count = *cnt;
  if (count > MAXC) count = MAXC;
  int w = threadIdx.x >> 6, l = threadIdx.x & 63;
  long pairs = (long)count << cpbsh;
  for (long p = (long)blockIdx.x * 4 + w; p < pairs; p += (long)gridDim.x * 4) {
    unsigned int cd = cand[p >> cpbsh];
    int q = cd >> 16;
    int blk = cd & 0xFFFF;
    int col = (int)(p & ((1 << cpbsh) - 1));
    int n = blk * ncols + col;
    if (col >= ncols || n >= N_TRAIN) continue;   // wave-uniform
    const float* xq = x + (size_t)q * DIM;
    const float* tn = Xt + (size_t)n * DIM;
    float s = 0.f;
#pragma unroll
    for (int i = 0; i < 12; ++i) {
      float d = xq[i * 64 + l] - tn[i * 64 + l];
      s = fmaf(d, d, s);
    }
#pragma unroll
    for (int sh = 1; sh < 64; sh <<= 1) s += __shfl_xor(s, sh);
    if (l == 0) {
      unsigned long long key =
          ((unsigned long long)__builtin_bit_cast(unsigned int, s) << 32) | (unsigned int)n;
      atomicMin(res + q, key);                // min d2, tie -> lowest index
    }
  }
}

// ---------------- Pass D: gather ----------------
__global__ void passD(const unsigned long long* __restrict__ res,
                      const float* __restrict__ Y, float* __restrict__ out) {
  int t = blockIdx.x * 256 + threadIdx.x;
  if (t < NQ * 24) {
    int q = t / 24, j = t - q * 24;
    unsigned int idx = (unsigned int)(res[q] & 0xFFFFFFFFu);
    out[t] = Y[(size_t)idx * 24 + j];
  }
}

extern "C" void kernel_launch(void* const* d_in, const int* in_sizes, int n_in,
                              void* d_out, int out_size, void* d_ws, size_t ws_size,
                              hipStream_t stream) {
  const float* x  = (const float*)d_in[0];   // [1024][768]
  const float* Xt = (const float*)d_in[1];   // [100000][768]
  const float* Y  = (const float*)d_in[2];   // [100000][24]
  float* out = (float*)d_out;                // [1024*24]
  char* ws = (char*)d_ws;
  unsigned long long* res  = (unsigned long long*)(ws);        // 8192 B
  unsigned int*       cnt  = (unsigned int*)(ws + 8192);       // 256 B
  unsigned int*       gmin = (unsigned int*)(ws + 8448);       // 4096 B
  unsigned int*       cand = (unsigned int*)(ws + 12544);      // 256 KB
  unsigned short*     Asw  = (unsigned short*)(ws + 274688);   // 1.5 MB
  float*              bmin = (float*)(ws + 1847552);           // 25.6 / 8.5 MB

  size_t needFine = 1847552ull + (size_t)NCHUNK * NQ * 3 * 4ull;  // ~27.5 MB
  int fine, bpq, cpbsh, ncols;
  if (ws_size >= needFine) { fine = 1; bpq = 3; cpbsh = 4; ncols = 16; }
  else                     { fine = 0; bpq = 1; cpbsh = 6; ncols = 48; }

  hipLaunchKernelGGL(initK,  dim3(1),      dim3(1024), 0, stream, res, gmin, cnt);
  hipLaunchKernelGGL(convA,  dim3(384),    dim3(256),  0, stream, x, Asw);
  hipLaunchKernelGGL(passA,  dim3(NCHUNK), dim3(512),  0, stream, Xt, Asw, bmin, fine);
  hipLaunchKernelGGL(passB1, dim3(256),    dim3(256),  0, stream, bmin, gmin, bpq);
  hipLaunchKernelGGL(passB2, dim3(256),    dim3(256),  0, stream, bmin, gmin, cnt, cand, bpq);
  hipLaunchKernelGGL(passC,  dim3(512),    dim3(256),  0, stream, x, Xt, cnt, cand, res, cpbsh, ncols);
  hipLaunchKernelGGL(passD,  dim3(96),     dim3(256),  0, stream, res, Y, out);
}

// Round 6
// 340.816 us; speedup vs baseline: 2.8386x; 2.8386x over previous
//
#include <hip/hip_runtime.h>

#define N_TRAIN 100000
#define DIM 768
#define NQ 1024
#define BN 48                  // cols per chunk; LDS 74KB -> 2 WGs/CU
#define NCHUNK 2084            // ceil(100000/48), tail chunk has 16 valid
#define MARGIN 6.0f
#define MAXC 65536

typedef __bf16 bf16x8 __attribute__((ext_vector_type(8)));
typedef float f32x4 __attribute__((ext_vector_type(4)));
typedef unsigned short u16x8 __attribute__((ext_vector_type(8)));

__device__ __forceinline__ unsigned short f2bf(float f) {
  unsigned int u = __builtin_bit_cast(unsigned int, f);
  u = (u + 0x7FFFu + ((u >> 16) & 1u)) >> 16;   // RNE fp32->bf16
  return (unsigned short)u;
}
__device__ __forceinline__ float bf2f(unsigned short h) {
  return __builtin_bit_cast(float, (unsigned int)h << 16);
}
// monotonic float<->uint for atomicMin over possibly-negative floats
__device__ __forceinline__ unsigned int fenc(float f) {
  unsigned int u = __builtin_bit_cast(unsigned int, f);
  return (u & 0x80000000u) ? ~u : (u | 0x80000000u);
}
__device__ __forceinline__ float fdec(unsigned int u) {
  u = (u & 0x80000000u) ? (u & 0x7FFFFFFFu) : ~u;
  return __builtin_bit_cast(float, u);
}

// ---------------- init ----------------
__global__ void initK(unsigned long long* res, unsigned int* gmin, unsigned int* cnt) {
  int t = threadIdx.x;
  res[t] = ~0ull;
  gmin[t] = 0xFFFFFFFFu;
  if (t == 0) *cnt = 0u;
}

// ------- convert queries to bf16, pre-swizzled MFMA A-fragment layout -------
// mfma_f32_16x16x32_bf16 A-operand: lane l -> row=l&15, k=(l>>4)*8..+7
// Asw[fragid=mf*24+ks][lane][8 bf16] -> coalesced 1KB wave loads, L2-resident
__global__ void convA(const float* __restrict__ x, unsigned short* __restrict__ Asw) {
  int t = blockIdx.x * 256 + threadIdx.x;   // 0..98303
  int l = t & 63;
  int fragid = t >> 6;                      // 0..1535
  int mf = fragid / 24;
  int ks = fragid - mf * 24;
  int row = mf * 16 + (l & 15);
  int k = ks * 32 + (l >> 4) * 8;
  const float* src = x + (size_t)row * DIM + k;
  u16x8 h;
#pragma unroll
  for (int i = 0; i < 8; ++i) h[i] = f2bf(src[i]);
  *(u16x8*)(Asw + (size_t)fragid * 512 + l * 8) = h;
}

// ---------------- Pass A: approx bf16 GEMM + block-min ----------------
// One WG per 48-column chunk. B-tile (full K=768) staged ONCE in 74KB LDS
// (bf16, XOR-swizzled); barrier-free ROLLED k-loop (full unroll caused
// scratch spill: R2-R5's hidden 1.1GB write traffic, VGPR capped at 64).
// Output bmin[chunk][q][cf]: WG-contiguous writes, plain stores.
__global__ __launch_bounds__(512, 4) void passA(
    const float* __restrict__ Xt, const unsigned short* __restrict__ Asw,
    float* __restrict__ bmin, int fine) {
  __shared__ __align__(16) unsigned short Bs[BN * DIM];  // 73728 B
  __shared__ float t2p[BN][8];
  __shared__ float t2s[BN];
  const int tid = threadIdx.x;
  const int chunk = blockIdx.x;

  // ---- stage: 48 train rows -> bf16 LDS (swizzled) + sum-of-squares ----
  if (tid < 384) {
    const int c = tid >> 3;      // local column (train row) 0..47
    const int sl = tid & 7;      // k-slice
    const int n = chunk * BN + c;
    float ss = 0.f;
    if (n < N_TRAIN) {
      const float* src = Xt + (size_t)n * DIM + sl * 8;
#pragma unroll
      for (int j = 0; j < 12; ++j) {
        f32x4 v0 = *(const f32x4*)(src + j * 64);
        f32x4 v1 = *(const f32x4*)(src + j * 64 + 4);
        u16x8 h;
        h[0] = f2bf(v0[0]); h[1] = f2bf(v0[1]); h[2] = f2bf(v0[2]); h[3] = f2bf(v0[3]);
        h[4] = f2bf(v1[0]); h[5] = f2bf(v1[1]); h[6] = f2bf(v1[2]); h[7] = f2bf(v1[3]);
#pragma unroll
        for (int i = 0; i < 8; ++i) { float f = bf2f(h[i]); ss = fmaf(f, f, ss); }
        int e = (c * DIM + sl * 8 + j * 64) ^ ((c & 7) << 3);
        *(u16x8*)(&Bs[e]) = h;
      }
    } else {
      u16x8 h;
#pragma unroll
      for (int i = 0; i < 8; ++i) h[i] = 0;
#pragma unroll
      for (int j = 0; j < 12; ++j) {
        int e = (c * DIM + sl * 8 + j * 64) ^ ((c & 7) << 3);
        *(u16x8*)(&Bs[e]) = h;
      }
    }
    t2p[c][sl] = ss;
  }
  __syncthreads();
  if (tid < BN) {
    float s = 0.f;
#pragma unroll
    for (int j = 0; j < 8; ++j) s += t2p[tid][j];
    t2s[tid] = (chunk * BN + tid < N_TRAIN) ? s : 3.0e38f;
  }
  __syncthreads();

  const int wid = tid >> 6;
  const int l = tid & 63;
  const int lc = l & 15;
  const int lg = l >> 4;

  for (int mt = 0; mt < 2; ++mt) {          // 2 m-tiles of 512 query rows
    f32x4 acc[4][3];
#pragma unroll
    for (int rf = 0; rf < 4; ++rf)
#pragma unroll
      for (int cf = 0; cf < 3; ++cf) {
        acc[rf][cf][0] = 0.f; acc[rf][cf][1] = 0.f;
        acc[rf][cf][2] = 0.f; acc[rf][cf][3] = 0.f;
      }
    const int mfbase = mt * 32 + wid * 4;   // wave owns 64 query rows = 4 row-frags
    for (int ks = 0; ks < 24; ++ks) {       // ROLLED: no unroll pragma (spill!)
      bf16x8 a[4], b[3];
#pragma unroll
      for (int rf = 0; rf < 4; ++rf)
        a[rf] = __builtin_bit_cast(bf16x8,
                  *(const u16x8*)(Asw + (size_t)((mfbase + rf) * 24 + ks) * 512 + l * 8));
#pragma unroll
      for (int cf = 0; cf < 3; ++cf) {
        int col = cf * 16 + lc;
        int idx = (col * DIM + ks * 32 + lg * 8) ^ ((col & 7) << 3);
        b[cf] = __builtin_bit_cast(bf16x8, *(const u16x8*)(&Bs[idx]));
      }
#pragma unroll
      for (int rf = 0; rf < 4; ++rf)
#pragma unroll
        for (int cf = 0; cf < 3; ++cf)
          acc[rf][cf] = __builtin_amdgcn_mfma_f32_16x16x32_bf16(a[rf], b[cf], acc[rf][cf], 0, 0, 0);
    }
    // ---- epilogue: d2' = t2 - 2*cross ; per-row mins; contiguous writes ----
    const int rowbase = mt * 512 + wid * 64;
#pragma unroll
    for (int rf = 0; rf < 4; ++rf) {
#pragma unroll
      for (int reg = 0; reg < 4; ++reg) {
        int row = rowbase + rf * 16 + lg * 4 + reg;
        if (fine) {                           // 3 blocks of 16 cols
#pragma unroll
          for (int cf = 0; cf < 3; ++cf) {
            float v = t2s[cf * 16 + lc] - 2.f * acc[rf][cf][reg];
#pragma unroll
            for (int s = 1; s < 16; s <<= 1) v = fminf(v, __shfl_xor(v, s));
            if (lc == 0)
              bmin[(size_t)chunk * (NQ * 3) + row * 3 + cf] = v;
          }
        } else {                              // one block of 48 cols
          float v = 3.0e38f;
#pragma unroll
          for (int cf = 0; cf < 3; ++cf)
            v = fminf(v, t2s[cf * 16 + lc] - 2.f * acc[rf][cf][reg]);
#pragma unroll
          for (int s = 1; s < 16; s <<= 1) v = fminf(v, __shfl_xor(v, s));
          if (lc == 0)
            bmin[(size_t)chunk * NQ + row] = v;
        }
      }
    }
  }
}

// ------- Pass B1: per-query global min (coalesced over q, atomicMin) -------
__global__ __launch_bounds__(256) void passB1(const float* __restrict__ bmin,
                                              unsigned int* __restrict__ gmin, int bpq) {
  int qg = blockIdx.x >> 4, cs = blockIdx.x & 15;
  int w = threadIdx.x >> 6, l = threadIdx.x & 63;
  int q = qg * 64 + l;
  float m = 3.0e38f;
  for (int j = cs * 4 + w; j < NCHUNK; j += 64) {
    const float* p = bmin + (size_t)j * (NQ * bpq) + q * bpq;
    for (int cf = 0; cf < bpq; ++cf) m = fminf(m, p[cf]);
  }
  __shared__ float sm[4][64];
  sm[w][l] = m;
  __syncthreads();
  if (threadIdx.x < 64) {
    float v = fminf(fminf(sm[0][l], sm[1][l]), fminf(sm[2][l], sm[3][l]));
    atomicMin(&gmin[q], fenc(v));
  }
}

// ------- Pass B2: emit candidate blocks within min+MARGIN -------
__global__ __launch_bounds__(256) void passB2(const float* __restrict__ bmin,
                                              const unsigned int* __restrict__ gmin,
                                              unsigned int* __restrict__ cnt,
                                              unsigned int* __restrict__ cand, int bpq) {
  int qg = blockIdx.x >> 4, cs = blockIdx.x & 15;
  int w = threadIdx.x >> 6, l = threadIdx.x & 63;
  int q = qg * 64 + l;
  float thr = fdec(gmin[q]) + MARGIN;
  for (int j = cs * 4 + w; j < NCHUNK; j += 64) {
    const float* p = bmin + (size_t)j * (NQ * bpq) + q * bpq;
    for (int cf = 0; cf < bpq; ++cf) {
      if (p[cf] <= thr) {
        unsigned int pos = atomicAdd(cnt, 1u);
        if (pos < MAXC) cand[pos] = ((unsigned int)q << 16) | (unsigned int)(j * bpq + cf);
      }
    }
  }
}

// ---------------- Pass C: exact fp32 re-rank of candidates ----------------
__global__ void passC(const float* __restrict__ x, const float* __restrict__ Xt,
                      const unsigned int* __restrict__ cnt, const unsigned int* __restrict__ cand,
                      unsigned long long* __restrict__ res, int cpbsh, int ncols) {
  unsigned int count = *cnt;
  if (count > MAXC) count = MAXC;
  int w = threadIdx.x >> 6, l = threadIdx.x & 63;
  long pairs = (long)count << cpbsh;
  for (long p = (long)blockIdx.x * 4 + w; p < pairs; p += (long)gridDim.x * 4) {
    unsigned int cd = cand[p >> cpbsh];
    int q = cd >> 16;
    int blk = cd & 0xFFFF;
    int col = (int)(p & ((1 << cpbsh) - 1));
    int n = blk * ncols + col;
    if (col >= ncols || n >= N_TRAIN) continue;   // wave-uniform
    const float* xq = x + (size_t)q * DIM;
    const float* tn = Xt + (size_t)n * DIM;
    float s = 0.f;
#pragma unroll
    for (int i = 0; i < 12; ++i) {
      float d = xq[i * 64 + l] - tn[i * 64 + l];
      s = fmaf(d, d, s);
    }
#pragma unroll
    for (int sh = 1; sh < 64; sh <<= 1) s += __shfl_xor(s, sh);
    if (l == 0) {
      unsigned long long key =
          ((unsigned long long)__builtin_bit_cast(unsigned int, s) << 32) | (unsigned int)n;
      atomicMin(res + q, key);                // min d2, tie -> lowest index
    }
  }
}

// ---------------- Pass D: gather ----------------
__global__ void passD(const unsigned long long* __restrict__ res,
                      const float* __restrict__ Y, float* __restrict__ out) {
  int t = blockIdx.x * 256 + threadIdx.x;
  if (t < NQ * 24) {
    int q = t / 24, j = t - q * 24;
    unsigned int idx = (unsigned int)(res[q] & 0xFFFFFFFFu);
    out[t] = Y[(size_t)idx * 24 + j];
  }
}

extern "C" void kernel_launch(void* const* d_in, const int* in_sizes, int n_in,
                              void* d_out, int out_size, void* d_ws, size_t ws_size,
                              hipStream_t stream) {
  const float* x  = (const float*)d_in[0];   // [1024][768]
  const float* Xt = (const float*)d_in[1];   // [100000][768]
  const float* Y  = (const float*)d_in[2];   // [100000][24]
  float* out = (float*)d_out;                // [1024*24]
  char* ws = (char*)d_ws;
  unsigned long long* res  = (unsigned long long*)(ws);        // 8192 B
  unsigned int*       cnt  = (unsigned int*)(ws + 8192);       // 256 B
  unsigned int*       gmin = (unsigned int*)(ws + 8448);       // 4096 B
  unsigned int*       cand = (unsigned int*)(ws + 12544);      // 256 KB
  unsigned short*     Asw  = (unsigned short*)(ws + 274688);   // 1.5 MB
  float*              bmin = (float*)(ws + 1847552);           // 25.6 / 8.5 MB

  size_t needFine = 1847552ull + (size_t)NCHUNK * NQ * 3 * 4ull;  // ~27.5 MB
  int fine, bpq, cpbsh, ncols;
  if (ws_size >= needFine) { fine = 1; bpq = 3; cpbsh = 4; ncols = 16; }
  else                     { fine = 0; bpq = 1; cpbsh = 6; ncols = 48; }

  hipLaunchKernelGGL(initK,  dim3(1),      dim3(1024), 0, stream, res, gmin, cnt);
  hipLaunchKernelGGL(convA,  dim3(384),    dim3(256),  0, stream, x, Asw);
  hipLaunchKernelGGL(passA,  dim3(NCHUNK), dim3(512),  0, stream, Xt, Asw, bmin, fine);
  hipLaunchKernelGGL(passB1, dim3(256),    dim3(256),  0, stream, bmin, gmin, bpq);
  hipLaunchKernelGGL(passB2, dim3(256),    dim3(256),  0, stream, bmin, gmin, cnt, cand, bpq);
  hipLaunchKernelGGL(passC,  dim3(512),    dim3(256),  0, stream, x, Xt, cnt, cand, res, cpbsh, ncols);
  hipLaunchKernelGGL(passD,  dim3(96),     dim3(256),  0, stream, res, Y, out);
}